// Round 7
// baseline (211.852 us; speedup 1.0000x reference)
//
#include <hip/hip_runtime.h>
#include <stdint.h>

#define B_ 32
#define S_ 32
#define P_ 2048
#define J_ 32
#define I_ 16

// one b-pair plane = [S][P][J=32] dwords = 8 MiB
#define PLSTRIDE ((size_t)S_ * P_ * 32)

typedef _Float16 half8_t __attribute__((ext_vector_type(8)));
typedef float f32x16 __attribute__((ext_vector_type(16)));

// fp16 unpack helpers (dword = {lo: b0, hi: b0+1} at one j)
__device__ inline float f16lo(uint32_t d) {
    return (float)__builtin_bit_cast(_Float16, (unsigned short)(d & 0xffffu));
}
__device__ inline float f16hi(uint32_t d) {
    return (float)__builtin_bit_cast(_Float16, (unsigned short)(d >> 16));
}

// =====================================================================
// Kernel 1 (MFMA, no LDS): per (s,p), C[b=32,j=32] = X[b,:].W[j,:]^T via
// one v_mfma_f32_32x32x16_f16. acc pairs (acc[2m],acc[2m+1]) = (b0,b0+1)
// same j packed to one dword, stored DIRECTLY to b-pair-plane layout
// U[plane][s][p][j]: plane=(m<<1)|lhi, b0 = ((2m)&3)+8*(m>>1)+4*lhi.
// R6: confirmed ~50us (dropped out of top-5; 82us with LDS transpose).
// =====================================================================
__global__ __launch_bounds__(256) void uhat_kernel(
        const float* __restrict__ W, const float* __restrict__ X,
        uint32_t* __restrict__ U) {
    const int tid  = threadIdx.x;
    const int lane = tid & 63;
    const int wave = tid >> 6;
    const int l31  = lane & 31;
    const int lhi  = lane >> 5;       // 0/1
    const int s    = blockIdx.y;
    const int p0   = blockIdx.x * 16 + wave * 4;

    // ---- load all 4 t-iters' W/X fragments up front (max ILP) ----
    float4 wv[4][2], xv[4][2];
    #pragma unroll
    for (int t = 0; t < 4; ++t) {
        const int p = p0 + t;
        const float* wr = W + (((size_t)s * P_ + p) * J_ + l31) * I_ + lhi * 8;
        wv[t][0] = *reinterpret_cast<const float4*>(wr);
        wv[t][1] = *reinterpret_cast<const float4*>(wr + 4);
        const float* xr = X + ((size_t)l31 * P_ + p) * I_ + lhi * 8;
        xv[t][0] = *reinterpret_cast<const float4*>(xr);
        xv[t][1] = *reinterpret_cast<const float4*>(xr + 4);
    }

    #pragma unroll
    for (int t = 0; t < 4; ++t) {
        const int p = p0 + t;
        half8_t A, Bf;
        A[0] = (_Float16)xv[t][0].x; A[1] = (_Float16)xv[t][0].y;
        A[2] = (_Float16)xv[t][0].z; A[3] = (_Float16)xv[t][0].w;
        A[4] = (_Float16)xv[t][1].x; A[5] = (_Float16)xv[t][1].y;
        A[6] = (_Float16)xv[t][1].z; A[7] = (_Float16)xv[t][1].w;
        Bf[0] = (_Float16)wv[t][0].x; Bf[1] = (_Float16)wv[t][0].y;
        Bf[2] = (_Float16)wv[t][0].z; Bf[3] = (_Float16)wv[t][0].w;
        Bf[4] = (_Float16)wv[t][1].x; Bf[5] = (_Float16)wv[t][1].y;
        Bf[6] = (_Float16)wv[t][1].z; Bf[7] = (_Float16)wv[t][1].w;

        f32x16 acc = {};
        acc = __builtin_amdgcn_mfma_f32_32x32x16_f16(A, Bf, acc, 0, 0, 0);

        // acc[r]: j = l31, b = (r&3)+8*(r>>2)+4*lhi. Pairs r=2m,2m+1 -> b0,b0+1.
        const size_t rowbase = ((size_t)s * P_ + p) * 32 + l31;
        #pragma unroll
        for (int m = 0; m < 8; ++m) {
            uint32_t lo = (uint32_t)__builtin_bit_cast(
                unsigned short, (_Float16)acc[2 * m]);       // b0   (RNE)
            uint32_t hi = (uint32_t)__builtin_bit_cast(
                unsigned short, (_Float16)acc[2 * m + 1]);   // b0+1 (RNE)
            const int plane = (m << 1) | lhi;
            U[(size_t)plane * PLSTRIDE + rowbase] = lo | (hi << 16);
        }
    }
}

// ---------- split-butterfly wave reduction of a 32-vector ----------
template <int MASK, int HALF>
__device__ inline void red_level(float* red, int lane) {
    const bool hi = (lane & MASK) != 0;
    #pragma unroll
    for (int k = 0; k < HALF; ++k) {
        float send = hi ? red[k] : red[k + HALF];
        float recv = __shfl_xor(send, MASK, 64);
        red[k] = (hi ? red[k + HALF] : red[k]) + recv;
    }
}

// =====================================================================
// Kernel 2: dynamic routing. One 1024-thread block per (plane, s) —
// solves BOTH problems (b0, b0+1) of the plane from the SAME dwords.
// Thread owns p-rows 2*tid, 2*tid+1: 64 dwords = 256B contiguous.
// R6 post-mortem: __launch_bounds__(1024) let compiler cap VGPR at 64
// -> a[64] spilled to scratch (WRITE_SIZE 106MB, FETCH 2.1x, 160us).
// Fix: min-waves arg 4 -> 128-VGPR cap, 1 block/CU, no spill.
// =====================================================================
__global__ __launch_bounds__(1024, 4) void routing_kernel(
        const uint32_t* __restrict__ U, float* __restrict__ out) {
    const int tid   = threadIdx.x;
    const int lane  = tid & 63;
    const int wid   = tid >> 6;           // 0..15
    const int plane = blockIdx.x & 15;
    const int s     = blockIdx.x >> 4;
    const int m     = plane >> 1;
    const int lhi   = plane & 1;
    const int b0    = ((2 * m) & 3) + 8 * (m >> 1) + 4 * lhi;

    __shared__ float sred[2][16][32];     // [parity][wave][j]
    __shared__ float vlds[2][32];
    __shared__ float scal[2][32];         // [parity][0..15]=max, [16..31]=sum

    // load my 2 rows (both parities): 64 dwords = 256B contiguous
    const uint32_t* ub = U + (size_t)plane * PLSTRIDE
                           + ((size_t)s * P_ + 2 * (size_t)tid) * 32;
    uint32_t a[64];
    #pragma unroll
    for (int k = 0; k < 16; ++k) {
        uint4 t = reinterpret_cast<const uint4*>(ub)[k];
        a[k * 4 + 0] = t.x; a[k * 4 + 1] = t.y;
        a[k * 4 + 2] = t.z; a[k * 4 + 3] = t.w;
    }
    // a[0..31] = row p0 (j=0..31), a[32..63] = row p1

    float lg[2][2] = {{0.f, 0.f}, {0.f, 0.f}};   // [parity][p0/p1] logits

    for (int it = 0; it < 3; ++it) {
        // ---- c = softmax(logits) over p, per parity ----
        float c[2][2];
        if (it == 0) {
            c[0][0] = c[0][1] = c[1][0] = c[1][1] = 1.0f / 2048.0f;
        } else {
            #pragma unroll
            for (int pi = 0; pi < 2; ++pi) {
                float mx = fmaxf(lg[pi][0], lg[pi][1]);
                #pragma unroll
                for (int msk = 32; msk >= 1; msk >>= 1)
                    mx = fmaxf(mx, __shfl_xor(mx, msk, 64));
                if (lane == 0) scal[pi][wid] = mx;
            }
            __syncthreads();
            #pragma unroll
            for (int pi = 0; pi < 2; ++pi) {
                float mx = scal[pi][0];
                #pragma unroll
                for (int w2 = 1; w2 < 16; ++w2) mx = fmaxf(mx, scal[pi][w2]);
                float e0 = __expf(lg[pi][0] - mx);
                float e1 = __expf(lg[pi][1] - mx);
                c[pi][0] = e0; c[pi][1] = e1;
                float zs = e0 + e1;
                #pragma unroll
                for (int msk = 32; msk >= 1; msk >>= 1)
                    zs += __shfl_xor(zs, msk, 64);
                if (lane == 0) scal[pi][16 + wid] = zs;
            }
            __syncthreads();
            #pragma unroll
            for (int pi = 0; pi < 2; ++pi) {
                float Z = 0.0f;
                #pragma unroll
                for (int w2 = 0; w2 < 16; ++w2) Z += scal[pi][16 + w2];
                float invZ = 1.0f / Z;
                c[pi][0] *= invZ; c[pi][1] *= invZ;
            }
        }

        // ---- per-parity: partial s_j, wave reduce, stash ----
        #pragma unroll
        for (int pi = 0; pi < 2; ++pi) {
            float red[32];
            if (pi == 0) {
                #pragma unroll
                for (int j = 0; j < 32; ++j)
                    red[j] = fmaf(c[0][0], f16lo(a[j]), c[0][1] * f16lo(a[32 + j]));
            } else {
                #pragma unroll
                for (int j = 0; j < 32; ++j)
                    red[j] = fmaf(c[1][0], f16hi(a[j]), c[1][1] * f16hi(a[32 + j]));
            }
            red_level<32, 16>(red, lane);
            red_level<16, 8>(red, lane);
            red_level<8, 4>(red, lane);
            red_level<4, 2>(red, lane);
            red_level<2, 1>(red, lane);
            red[0] += __shfl_xor(red[0], 1, 64);
            if ((lane & 1) == 0) sred[pi][wid][lane >> 1] = red[0];
        }
        __syncthreads();

        // ---- cross-wave finalize + squash: tid 0..63 = (parity, j) ----
        if (tid < 64) {
            const int pi = tid >> 5, j = tid & 31;
            float sv = 0.0f;
            #pragma unroll
            for (int w2 = 0; w2 < 16; ++w2) sv += sred[pi][w2][j];
            float sq = sv * sv;
            #pragma unroll
            for (int msk = 16; msk >= 1; msk >>= 1)
                sq += __shfl_xor(sq, msk, 64);   // stays within 32-group
            float n = sqrtf(sq);
            float scale = sq / ((1.0f + sq) * (n + 1e-7f));
            float v = sv * scale;
            vlds[pi][j] = v;
            if (it == 2) out[((size_t)(b0 + pi) * S_ + s) * J_ + j] = v;
        }
        __syncthreads();

        // ---- agreement + logit update ----
        if (it < 2) {
            float ag00 = 0.f, ag01 = 0.f, ag10 = 0.f, ag11 = 0.f;
            #pragma unroll
            for (int j = 0; j < 32; ++j) {
                float v0 = vlds[0][j], v1 = vlds[1][j];
                uint32_t d0 = a[j], d1 = a[32 + j];
                ag00 = fmaf(v0, f16lo(d0), ag00);
                ag01 = fmaf(v0, f16lo(d1), ag01);
                ag10 = fmaf(v1, f16hi(d0), ag10);
                ag11 = fmaf(v1, f16hi(d1), ag11);
            }
            lg[0][0] += ag00; lg[0][1] += ag01;
            lg[1][0] += ag10; lg[1][1] += ag11;
        }
    }
}

extern "C" void kernel_launch(void* const* d_in, const int* in_sizes, int n_in,
                              void* d_out, int out_size, void* d_ws, size_t ws_size,
                              hipStream_t stream) {
    (void)in_sizes; (void)n_in; (void)out_size;
    const float* X = (const float*)d_in[0];        // [B,P,I] fp32
    const float* W = (const float*)d_in[1];        // [S,P,J,I] fp32
    float* out     = (float*)d_out;                // [B,S,J] fp32
    uint32_t* U    = (uint32_t*)d_ws;              // fp16 u_hat, b-pair planes

    const size_t need = (size_t)B_ * S_ * P_ * J_ * 2;  // 128 MiB
    if (ws_size < need) return;  // cannot run without scratch

    dim3 g1(P_ / 16, S_);
    uhat_kernel<<<g1, 256, 0, stream>>>(W, X, U);
    routing_kernel<<<16 * S_, 1024, 0, stream>>>(U, out);
}

// Round 8
// 122.363 us; speedup vs baseline: 1.7313x; 1.7313x over previous
//
#include <hip/hip_runtime.h>
#include <stdint.h>

#define B_ 32
#define S_ 32
#define P_ 2048
#define J_ 32
#define I_ 16

// one b-pair plane = [S][P][J=32] dwords = 8 MiB
#define PLSTRIDE ((size_t)S_ * P_ * 32)

typedef _Float16 half8_t __attribute__((ext_vector_type(8)));
typedef float f32x16 __attribute__((ext_vector_type(16)));

// fp16 unpack helpers (packed dword = {lo: j-even, hi: j-odd})
__device__ inline float f16lo(uint32_t d) {
    return (float)__builtin_bit_cast(_Float16, (unsigned short)(d & 0xffffu));
}
__device__ inline float f16hi(uint32_t d) {
    return (float)__builtin_bit_cast(_Float16, (unsigned short)(d >> 16));
}

// =====================================================================
// Kernel 1 (MFMA, no LDS): per (s,p), C[b=32,j=32] = X[b,:].W[j,:]^T via
// one v_mfma_f32_32x32x16_f16. acc pairs (acc[2m],acc[2m+1]) = (b0,b0+1)
// same j packed to one dword, stored DIRECTLY to b-pair-plane layout
// U[plane][s][p][j]: plane=(m<<1)|lhi, b0 = ((2m)&3)+8*(m>>1)+4*lhi.
// R6/R7: confirmed ~50us. UNCHANGED.
// =====================================================================
__global__ __launch_bounds__(256) void uhat_kernel(
        const float* __restrict__ W, const float* __restrict__ X,
        uint32_t* __restrict__ U) {
    const int tid  = threadIdx.x;
    const int lane = tid & 63;
    const int wave = tid >> 6;
    const int l31  = lane & 31;
    const int lhi  = lane >> 5;       // 0/1
    const int s    = blockIdx.y;
    const int p0   = blockIdx.x * 16 + wave * 4;

    float4 wv[4][2], xv[4][2];
    #pragma unroll
    for (int t = 0; t < 4; ++t) {
        const int p = p0 + t;
        const float* wr = W + (((size_t)s * P_ + p) * J_ + l31) * I_ + lhi * 8;
        wv[t][0] = *reinterpret_cast<const float4*>(wr);
        wv[t][1] = *reinterpret_cast<const float4*>(wr + 4);
        const float* xr = X + ((size_t)l31 * P_ + p) * I_ + lhi * 8;
        xv[t][0] = *reinterpret_cast<const float4*>(xr);
        xv[t][1] = *reinterpret_cast<const float4*>(xr + 4);
    }

    #pragma unroll
    for (int t = 0; t < 4; ++t) {
        const int p = p0 + t;
        half8_t A, Bf;
        A[0] = (_Float16)xv[t][0].x; A[1] = (_Float16)xv[t][0].y;
        A[2] = (_Float16)xv[t][0].z; A[3] = (_Float16)xv[t][0].w;
        A[4] = (_Float16)xv[t][1].x; A[5] = (_Float16)xv[t][1].y;
        A[6] = (_Float16)xv[t][1].z; A[7] = (_Float16)xv[t][1].w;
        Bf[0] = (_Float16)wv[t][0].x; Bf[1] = (_Float16)wv[t][0].y;
        Bf[2] = (_Float16)wv[t][0].z; Bf[3] = (_Float16)wv[t][0].w;
        Bf[4] = (_Float16)wv[t][1].x; Bf[5] = (_Float16)wv[t][1].y;
        Bf[6] = (_Float16)wv[t][1].z; Bf[7] = (_Float16)wv[t][1].w;

        f32x16 acc = {};
        acc = __builtin_amdgcn_mfma_f32_32x32x16_f16(A, Bf, acc, 0, 0, 0);

        const size_t rowbase = ((size_t)s * P_ + p) * 32 + l31;
        #pragma unroll
        for (int m = 0; m < 8; ++m) {
            uint32_t lo = (uint32_t)__builtin_bit_cast(
                unsigned short, (_Float16)acc[2 * m]);       // b0   (RNE)
            uint32_t hi = (uint32_t)__builtin_bit_cast(
                unsigned short, (_Float16)acc[2 * m + 1]);   // b0+1 (RNE)
            const int plane = (m << 1) | lhi;
            U[(size_t)plane * PLSTRIDE + rowbase] = lo | (hi << 16);
        }
    }
}

// ---------- split-butterfly wave reduction of a 32-vector ----------
template <int MASK, int HALF>
__device__ inline void red_level(float* red, int lane) {
    const bool hi = (lane & MASK) != 0;
    #pragma unroll
    for (int k = 0; k < HALF; ++k) {
        float send = hi ? red[k] : red[k + HALF];
        float recv = __shfl_xor(send, MASK, 64);
        red[k] = (hi ? red[k + HALF] : red[k]) + recv;
    }
}

// =====================================================================
// Kernel 2: dynamic routing, ONE (b,s) problem per block (R5's proven
// a[32] shape; R6/R7's a[64] spilled at the 64-VGPR 1024-thread cap).
// The block extracts its parity from the plane dwords: a[k] =
// {u[row][2k], u[row][2k+1]} packed fp16. Partner blocks (two parities
// of one slab) are mapped to the SAME XCD 8 hw-dispatches apart so the
// second read of the 256KB slab hits L2 (hw i -> logical (i&7)*128+i/8).
// =====================================================================
__global__ __launch_bounds__(1024) void routing_kernel(
        const uint32_t* __restrict__ U, float* __restrict__ out) {
    const int tid  = threadIdx.x;
    const int lane = tid & 63;
    const int wid  = tid >> 6;            // 0..15

    // pair-on-same-XCD logical id
    const int hw   = blockIdx.x;          // 0..1023
    const int L    = (hw & 7) * 128 + (hw >> 3);
    const int par  = L & 1;
    const int pairIdx = L >> 1;           // 0..511
    const int plane = pairIdx >> 5;
    const int s     = pairIdx & 31;
    const int m     = plane >> 1;
    const int lhi   = plane & 1;
    const int b     = ((2 * m) & 3) + 8 * (m >> 1) + 4 * lhi + par;

    __shared__ float sred[16 * 32];       // per-wave 32-vector partials
    __shared__ float vlds[32];
    __shared__ float scal[32];            // [0..15] max, [16..31] sum

    // rows 2*tid, 2*tid+1: 64 dwords contiguous; extract parity -> a[32]
    // chunked (16 dwords at a time) + sched_barrier so the compiler
    // can't hoist all 64 transient dwords (that was R6's spill).
    const uint4* ub4 = reinterpret_cast<const uint4*>(
        U + (size_t)plane * PLSTRIDE + ((size_t)s * P_ + 2 * (size_t)tid) * 32);
    uint32_t a[32];
    #pragma unroll
    for (int c = 0; c < 4; ++c) {
        uint4 q0 = ub4[c * 4 + 0];
        uint4 q1 = ub4[c * 4 + 1];
        uint4 q2 = ub4[c * 4 + 2];
        uint4 q3 = ub4[c * 4 + 3];
        uint32_t D[16] = {q0.x, q0.y, q0.z, q0.w, q1.x, q1.y, q1.z, q1.w,
                          q2.x, q2.y, q2.z, q2.w, q3.x, q3.y, q3.z, q3.w};
        if (par == 0) {
            #pragma unroll
            for (int k = 0; k < 8; ++k)
                a[c * 8 + k] = (D[2 * k] & 0xffffu) | (D[2 * k + 1] << 16);
        } else {
            #pragma unroll
            for (int k = 0; k < 8; ++k)
                a[c * 8 + k] = (D[2 * k] >> 16) | (D[2 * k + 1] & 0xffff0000u);
        }
        __builtin_amdgcn_sched_barrier(0);
    }
    // a[0..15] = row p0 (j-pair dwords), a[16..31] = row p1

    float bp0 = 0.0f, bp1 = 0.0f;         // routing logits for my two p's

    for (int it = 0; it < 3; ++it) {
        // ---- c = softmax(b) over p ----
        float c0, c1;
        if (it == 0) {
            c0 = c1 = 1.0f / 2048.0f;     // softmax of zeros, exact
        } else {
            float mx = fmaxf(bp0, bp1);
            #pragma unroll
            for (int msk = 32; msk >= 1; msk >>= 1)
                mx = fmaxf(mx, __shfl_xor(mx, msk, 64));
            if (lane == 0) scal[wid] = mx;
            __syncthreads();
            mx = scal[0];
            #pragma unroll
            for (int w2 = 1; w2 < 16; ++w2) mx = fmaxf(mx, scal[w2]);
            float e0 = __expf(bp0 - mx);
            float e1 = __expf(bp1 - mx);
            float zs = e0 + e1;
            #pragma unroll
            for (int msk = 32; msk >= 1; msk >>= 1)
                zs += __shfl_xor(zs, msk, 64);
            if (lane == 0) scal[16 + wid] = zs;
            __syncthreads();
            float Z = 0.0f;
            #pragma unroll
            for (int w2 = 0; w2 < 16; ++w2) Z += scal[16 + w2];
            float invZ = 1.0f / Z;
            c0 = e0 * invZ;
            c1 = e1 * invZ;
        }

        // ---- per-thread partial s_j = c0*u[p0][j] + c1*u[p1][j] ----
        float red[32];
        #pragma unroll
        for (int k = 0; k < 16; ++k) {
            uint32_t d0 = a[k], d1 = a[16 + k];
            red[2 * k]     = fmaf(c0, f16lo(d0), c1 * f16lo(d1));
            red[2 * k + 1] = fmaf(c0, f16hi(d0), c1 * f16hi(d1));
        }
        // ---- wave reduce-scatter (31 shfl total) ----
        red_level<32, 16>(red, lane);
        red_level<16, 8>(red, lane);
        red_level<8, 4>(red, lane);
        red_level<4, 2>(red, lane);
        red_level<2, 1>(red, lane);
        red[0] += __shfl_xor(red[0], 1, 64);   // lane holds s_{lane>>1} wave-sum
        if ((lane & 1) == 0) sred[wid * 32 + (lane >> 1)] = red[0];
        __syncthreads();

        // ---- cross-wave finalize + squash (first 32 threads) ----
        if (tid < 32) {
            float sv = 0.0f;
            #pragma unroll
            for (int w2 = 0; w2 < 16; ++w2) sv += sred[w2 * 32 + tid];
            float sq = sv * sv;
            #pragma unroll
            for (int msk = 16; msk >= 1; msk >>= 1)
                sq += __shfl_xor(sq, msk, 64);
            float n = sqrtf(sq);
            float scale = sq / ((1.0f + sq) * (n + 1e-7f));
            float v = sv * scale;
            vlds[tid] = v;
            if (it == 2) out[((size_t)b * S_ + s) * J_ + tid] = v;
        }
        __syncthreads();

        // ---- agreement + logit update (not needed after last iter) ----
        if (it < 2) {
            const float2* vl2 = reinterpret_cast<const float2*>(vlds);
            float ag0 = 0.0f, ag1 = 0.0f;
            #pragma unroll
            for (int k = 0; k < 16; ++k) {
                float2 vk = vl2[k];               // v[2k], v[2k+1] (LDS broadcast)
                uint32_t d0 = a[k], d1 = a[16 + k];
                ag0 = fmaf(vk.x, f16lo(d0), ag0);
                ag0 = fmaf(vk.y, f16hi(d0), ag0);
                ag1 = fmaf(vk.x, f16lo(d1), ag1);
                ag1 = fmaf(vk.y, f16hi(d1), ag1);
            }
            bp0 += ag0;
            bp1 += ag1;
        }
    }
}

extern "C" void kernel_launch(void* const* d_in, const int* in_sizes, int n_in,
                              void* d_out, int out_size, void* d_ws, size_t ws_size,
                              hipStream_t stream) {
    (void)in_sizes; (void)n_in; (void)out_size;
    const float* X = (const float*)d_in[0];        // [B,P,I] fp32
    const float* W = (const float*)d_in[1];        // [S,P,J,I] fp32
    float* out     = (float*)d_out;                // [B,S,J] fp32
    uint32_t* U    = (uint32_t*)d_ws;              // fp16 u_hat, b-pair planes

    const size_t need = (size_t)B_ * S_ * P_ * J_ * 2;  // 128 MiB
    if (ws_size < need) return;  // cannot run without scratch

    dim3 g1(P_ / 16, S_);
    uhat_kernel<<<g1, 256, 0, stream>>>(W, X, U);
    routing_kernel<<<16 * S_ * 2, 1024, 0, stream>>>(U, out);
}